// Round 11
// baseline (344.045 us; speedup 1.0000x reference)
//
#include <hip/hip_runtime.h>
#include <math.h>

// Problem constants (match reference)
#define NQ 16384
#define NK 7933
#define DI 1024
#define HD 512
#define RANK_TARGET 11469   // NQ - int(0.3*NQ): 0-based ascending rank of thre

typedef __bf16 bf16x8 __attribute__((ext_vector_type(8)));
typedef float  f32x4  __attribute__((ext_vector_type(4)));

#define GLOAD_LDS16(g, l)                                                     \
  __builtin_amdgcn_global_load_lds(                                           \
      (const __attribute__((address_space(1))) void*)(g),                     \
      (__attribute__((address_space(3))) void*)(l), 16, 0, 0)

__device__ __forceinline__ unsigned mapf(float f) {
  unsigned b = __float_as_uint(f);
  return (b & 0x80000000u) ? ~b : (b | 0x80000000u);
}

__device__ __forceinline__ bf16x8 cvt8(float4 a, float4 b) {
  bf16x8 o;
  o[0] = (__bf16)a.x; o[1] = (__bf16)a.y; o[2] = (__bf16)a.z; o[3] = (__bf16)a.w;
  o[4] = (__bf16)b.x; o[5] = (__bf16)b.y; o[6] = (__bf16)b.z; o[7] = (__bf16)b.w;
  return o;
}

// ---------------------------------------------------------------------------
// Kernel 1: fp32 -> bf16 for wq_w, wk_w, key_x. Block 0 zeroes v/z/scf
// (1088 uints: v[512], z[512], scf[64] incl. the two last-block tickets).
// ---------------------------------------------------------------------------
__global__ void conv_wk(const float* __restrict__ wq, const float* __restrict__ wk,
                        const float* __restrict__ key,
                        __bf16* __restrict__ wqbf, __bf16* __restrict__ wkbf,
                        __bf16* __restrict__ kbf, unsigned* __restrict__ zero_region) {
  if (blockIdx.x == 0) {
    for (int j = threadIdx.x; j < 1088; j += 256) zero_region[j] = 0u;
  }
  const int NK8 = NK * DI / 8;   // 1,015,424
  const int W8  = HD * DI / 8;   // 65,536
  const int total = NK8 + 2 * W8;
  int i = blockIdx.x * blockDim.x + threadIdx.x;
  int stride = gridDim.x * blockDim.x;
  for (; i < total; i += stride) {
    const float* s; __bf16* d; int j;
    if (i < NK8)            { s = key; d = kbf;  j = i; }
    else if (i < NK8 + W8)  { s = wq;  d = wqbf; j = i - NK8; }
    else                    { s = wk;  d = wkbf; j = i - NK8 - W8; }
    float4 a = ((const float4*)s)[2 * j];
    float4 b = ((const float4*)s)[2 * j + 1];
    ((bf16x8*)d)[j] = cvt8(a, b);
  }
}

// ---------------------------------------------------------------------------
// Mega kernel (r9-identical, the 76 µs measured version), 636 blocks x 512
// threads, 80 KB LDS -> 2 blocks/CU. Blocks 0..123: k-GEMM 64x512 (BK=64,
// sA dbuf + sB single-buffer, fused v epilogue; ssrow aliases dead sA).
// Blocks 124..635: q-GEMM 64x256 reading fp32 query directly.
// ---------------------------------------------------------------------------
__global__ __launch_bounds__(512, 4)
void mega_gemms(const __bf16* __restrict__ kbf, const __bf16* __restrict__ wkbf,
                const float* __restrict__ wk_b, const float* __restrict__ wa,
                float* __restrict__ v,
                const float* __restrict__ query, const __bf16* __restrict__ wqbf,
                const float* __restrict__ wq_b, float* __restrict__ qtanh) {
  __shared__ __align__(16) char smem[81920];
  const int bid = blockIdx.x;
  const int tid = threadIdx.x;
  const int lane = tid & 63;
  const int wave = tid >> 6;                    // 0..7
  const int srow = lane >> 3;                   // 0..7 row within segment
  const int scol = ((lane & 7) ^ srow) << 3;    // swizzled col (bf16 units)
  const int lrow = lane & 15;
  const int chi  = lane >> 4;                   // 0..3
  constexpr int K = DI;

  if (bid < 124) {
    // ---------------- k path: 64x512 tile, fused v epilogue ----------------
    __bf16* sA = (__bf16*)smem;                 // 2 x 4096 elems (16 KB dbuf)
    __bf16* sB = (__bf16*)(smem + 16384);       // 32768 elems (64 KB single)
    float* ssrow = (float*)smem;                // aliases sA (dead after K-loop)
    const int m0 = bid * 64;

    int gaA = m0 + wave * 8 + srow; if (gaA > NK - 1) gaA = NK - 1;
    const __bf16* Ap = kbf + (size_t)gaA * K + scol;
    const __bf16* Bp[8];
#pragma unroll
    for (int c = 0; c < 8; ++c)
      Bp[c] = wkbf + (size_t)(wave * 64 + c * 8 + srow) * K + scol;

    f32x4 acc[4][4] = {};

    GLOAD_LDS16(Ap, &sA[wave * 512]);
#pragma unroll
    for (int c = 0; c < 8; ++c)
      GLOAD_LDS16(Bp[c], &sB[(wave * 8 + c) * 512]);
    __syncthreads();

    int buf = 0;
    for (int t = 0; t < 16; ++t) {
      const int kk = t * 64;
      if (t < 15)
        GLOAD_LDS16(Ap + kk + 64, &sA[(buf ^ 1) * 4096 + wave * 512]);
      const __bf16* sAc = sA + buf * 4096;
#pragma unroll
      for (int ks = 0; ks < 64; ks += 32) {
        const int cc = (ks >> 3) + chi;
        const int sw = ((cc ^ (lrow & 7)) << 3);
        bf16x8 af[4], bfr[4];
#pragma unroll
        for (int mi = 0; mi < 4; ++mi)
          af[mi] = *(const bf16x8*)(&sAc[(mi * 16 + lrow) * 64 + sw]);
#pragma unroll
        for (int ni = 0; ni < 4; ++ni)
          bfr[ni] = *(const bf16x8*)(&sB[(wave * 64 + ni * 16 + lrow) * 64 + sw]);
#pragma unroll
        for (int mi = 0; mi < 4; ++mi)
#pragma unroll
          for (int ni = 0; ni < 4; ++ni)
            acc[mi][ni] = __builtin_amdgcn_mfma_f32_16x16x32_bf16(af[mi], bfr[ni], acc[mi][ni], 0, 0, 0);
      }
      if (t < 15) {
        __syncthreads();                 // sB readers done; A(t+1) landed
#pragma unroll
        for (int c = 0; c < 8; ++c)      // overwrite sB with B(t+1)
          GLOAD_LDS16(Bp[c] + kk + 64, &sB[(wave * 8 + c) * 512]);
        __syncthreads();                 // B(t+1) resident
        buf ^= 1;
      }
    }

    // fused epilogue: tanh, row-norm, v accumulation (no ktanh store)
    __syncthreads();                     // all sA reads retired before aliasing
    if (tid < 64) ssrow[tid] = 0.f;
    __syncthreads();

    float b4[4];
#pragma unroll
    for (int ni = 0; ni < 4; ++ni) b4[ni] = wk_b[wave * 64 + ni * 16 + lrow];

#pragma unroll
    for (int mi = 0; mi < 4; ++mi)
#pragma unroll
      for (int ni = 0; ni < 4; ++ni)
#pragma unroll
        for (int r = 0; r < 4; ++r)
          acc[mi][ni][r] = tanhf(acc[mi][ni][r] + b4[ni]);

#pragma unroll
    for (int mi = 0; mi < 4; ++mi)
#pragma unroll
      for (int r = 0; r < 4; ++r) {
        float ps = 0.f;
#pragma unroll
        for (int ni = 0; ni < 4; ++ni) ps += acc[mi][ni][r] * acc[mi][ni][r];
#pragma unroll
        for (int off = 1; off < 16; off <<= 1) ps += __shfl_xor(ps, off);
        if ((lane & 15) == 0)
          atomicAdd(&ssrow[mi * 16 + (lane >> 4) * 4 + r], ps);
      }
    __syncthreads();

    if (tid < 64) {
      int grow = m0 + tid;
      float s = 0.f;
      if (grow < NK) s = wa[grow] / fmaxf(sqrtf(ssrow[tid]), 1e-12f);
      ssrow[tid] = s;                    // replace ss with scale (0 for tail)
    }
    __syncthreads();

    float sc[4][4];
#pragma unroll
    for (int mi = 0; mi < 4; ++mi)
#pragma unroll
      for (int r = 0; r < 4; ++r)
        sc[mi][r] = ssrow[mi * 16 + (lane >> 4) * 4 + r];

#pragma unroll
    for (int ni = 0; ni < 4; ++ni) {
      float cs = 0.f;
#pragma unroll
      for (int mi = 0; mi < 4; ++mi)
#pragma unroll
        for (int r = 0; r < 4; ++r)
          cs += acc[mi][ni][r] * sc[mi][r];
      cs += __shfl_xor(cs, 16);
      cs += __shfl_xor(cs, 32);
      if (lane < 16) atomicAdd(&v[wave * 64 + ni * 16 + lane], cs);
    }
  } else {
    // ---------------- q path: 64x256 tile, fp32 A from global --------------
    __bf16* sA = (__bf16*)smem;                 // 2 x 4096 elems (16 KB dbuf)
    __bf16* sB = (__bf16*)(smem + 16384);       // 2 x 16384 elems (64 KB dbuf)
    const int qi = bid - 124;                   // 0..511
    const int m0 = (qi >> 1) * 64;
    const int n0 = (qi & 1) * 256;
    const int wr = wave >> 2;                   // 0..1
    const int wc = wave & 3;                    // 0..3

    const int arow = tid >> 3;                  // 0..63
    const int acb  = tid & 7;                   // 0..7
    const int aoff = arow * 64 + ((acb ^ (arow & 7)) << 3);
    const float* ap = query + (size_t)(m0 + arow) * K + acb * 8;

    const __bf16* Bp0 = wqbf + (size_t)(n0 + (wave * 4 + 0) * 8 + srow) * K + scol;
    const __bf16* Bp1 = wqbf + (size_t)(n0 + (wave * 4 + 1) * 8 + srow) * K + scol;
    const __bf16* Bp2 = wqbf + (size_t)(n0 + (wave * 4 + 2) * 8 + srow) * K + scol;
    const __bf16* Bp3 = wqbf + (size_t)(n0 + (wave * 4 + 3) * 8 + srow) * K + scol;

    f32x4 acc[2][4] = {};

    {  // prologue: stage tile 0
      float4 x0 = *(const float4*)(ap);
      float4 x1 = *(const float4*)(ap + 4);
      GLOAD_LDS16(Bp0, &sB[(wave * 4 + 0) * 512]);
      GLOAD_LDS16(Bp1, &sB[(wave * 4 + 1) * 512]);
      GLOAD_LDS16(Bp2, &sB[(wave * 4 + 2) * 512]);
      GLOAD_LDS16(Bp3, &sB[(wave * 4 + 3) * 512]);
      *(bf16x8*)&sA[aoff] = cvt8(x0, x1);
      __syncthreads();
    }

    int buf = 0;
    for (int t = 0; t < 16; ++t) {
      const int kk = t * 64;
      float4 x0, x1;
      if (t < 15) {
        x0 = *(const float4*)(ap + kk + 64);     // A loads first (oldest VMEM)
        x1 = *(const float4*)(ap + kk + 68);
        const int ob = buf ^ 1;
        GLOAD_LDS16(Bp0 + kk + 64, &sB[ob * 16384 + (wave * 4 + 0) * 512]);
        GLOAD_LDS16(Bp1 + kk + 64, &sB[ob * 16384 + (wave * 4 + 1) * 512]);
        GLOAD_LDS16(Bp2 + kk + 64, &sB[ob * 16384 + (wave * 4 + 2) * 512]);
        GLOAD_LDS16(Bp3 + kk + 64, &sB[ob * 16384 + (wave * 4 + 3) * 512]);
      }
      const __bf16* sAc = sA + buf * 4096;
      const __bf16* sBc = sB + buf * 16384;
#pragma unroll
      for (int ks = 0; ks < 64; ks += 32) {
        const int cc = (ks >> 3) + chi;
        const int sw = ((cc ^ (lrow & 7)) << 3);
        bf16x8 af[2], bfr[4];
        af[0] = *(const bf16x8*)(&sAc[(wr * 32 + lrow) * 64 + sw]);
        af[1] = *(const bf16x8*)(&sAc[(wr * 32 + 16 + lrow) * 64 + sw]);
#pragma unroll
        for (int ni = 0; ni < 4; ++ni)
          bfr[ni] = *(const bf16x8*)(&sBc[(wc * 64 + ni * 16 + lrow) * 64 + sw]);
#pragma unroll
        for (int ni = 0; ni < 4; ++ni) {
          acc[0][ni] = __builtin_amdgcn_mfma_f32_16x16x32_bf16(af[0], bfr[ni], acc[0][ni], 0, 0, 0);
          acc[1][ni] = __builtin_amdgcn_mfma_f32_16x16x32_bf16(af[1], bfr[ni], acc[1][ni], 0, 0, 0);
        }
      }
      if (t < 15) {
        *(bf16x8*)&sA[(buf ^ 1) * 4096 + aoff] = cvt8(x0, x1);  // waits A regs
        __syncthreads();                  // retires B prefetch + sA write
        buf ^= 1;
      }
    }

    // epilogue: qtanh only (A1 handled by a1_select)
    const int rbase = m0 + wr * 32 + ((lane >> 4) << 2);
    const int cbase = n0 + wc * 64 + (lane & 15);
    float b4[4];
#pragma unroll
    for (int ni = 0; ni < 4; ++ni) b4[ni] = wq_b[cbase + ni * 16];
#pragma unroll
    for (int mi = 0; mi < 2; ++mi)
#pragma unroll
      for (int r = 0; r < 4; ++r) {
        int grow = rbase + mi * 16 + r;
#pragma unroll
        for (int ni = 0; ni < 4; ++ni)
          qtanh[(size_t)grow * HD + cbase + ni * 16] =
              tanhf(acc[mi][ni][r] + b4[ni]);
      }
  }
}

// ---------------------------------------------------------------------------
// Kernel 3: A1[r] = (qtanh[r].v)/max(||qtanh[r]||,1e-12) + wa_b.
// 256 blocks x 1024 threads (all CUs); each 16-lane group owns ONE row
// (8 independent float4 loads, single 4-step shuffle reduce). Single sweep:
// 256 x 16 waves x 4 groups = 16384 rows. LAST block (ticket=255) runs the
// exact rank-11469 select AND computes S = sum(exp(thr(A1)-thre)) -> scf.
// ---------------------------------------------------------------------------
__global__ __launch_bounds__(1024)
void a1_select(const float* __restrict__ qt, const float* __restrict__ v,
               const float* __restrict__ wa_b, float* __restrict__ A1,
               float* __restrict__ scf, unsigned* __restrict__ cnt) {
  __shared__ unsigned wred1[16], wred2[16], wred3[16];
  __shared__ float fred[16];
  __shared__ unsigned s_res;
  __shared__ unsigned s_t;
  const int tid = threadIdx.x, lane = tid & 63, wave = tid >> 6;  // wave 0..15
  const int grp = lane >> 4;                   // 0..3: row group within wave
  const int gl  = lane & 15;                   // lane within group
  const float wab = wa_b[0];

  // preload v slice for this lane: chunk c covers cols c*128 + gl*8 .. +7
  float4 vv0[4], vv1[4];
#pragma unroll
  for (int c = 0; c < 4; ++c) {
    vv0[c] = *(const float4*)(v + c * 128 + gl * 8);
    vv1[c] = *(const float4*)(v + c * 128 + gl * 8 + 4);
  }

  {
    const int r = blockIdx.x * 64 + wave * 4 + grp;      // 0..16383, unique
    const float* row = qt + (size_t)r * HD + gl * 8;
    float dot = 0.f, ss = 0.f;
#pragma unroll
    for (int c = 0; c < 4; ++c) {
      float4 u  = *(const float4*)(row + c * 128);
      float4 w2 = *(const float4*)(row + c * 128 + 4);
      dot += u.x * vv0[c].x + u.y * vv0[c].y + u.z * vv0[c].z + u.w * vv0[c].w
           + w2.x * vv1[c].x + w2.y * vv1[c].y + w2.z * vv1[c].z + w2.w * vv1[c].w;
      ss  += u.x * u.x + u.y * u.y + u.z * u.z + u.w * u.w
           + w2.x * w2.x + w2.y * w2.y + w2.z * w2.z + w2.w * w2.w;
    }
#pragma unroll
    for (int off = 1; off < 16; off <<= 1) {
      dot += __shfl_xor(dot, off);
      ss  += __shfl_xor(ss, off);
    }
    if (gl == 0) A1[r] = dot / fmaxf(sqrtf(ss), 1e-12f) + wab;
  }

  // last-block ticket: release fence, count, only last block proceeds
  __threadfence();
  __syncthreads();
  if (tid == 0) s_t = atomicAdd(cnt, 1u);
  __syncthreads();
  if (s_t != 255) return;
  __threadfence();                               // acquire side

  volatile const float* A1v = A1;
  float a1l[16];
  unsigned kloc[16];
#pragma unroll 4
  for (int j = 0; j < 16; ++j) {
    float x = A1v[j * 1024 + tid];
    a1l[j] = x;
    kloc[j] = mapf(x);
  }
  if (tid == 0) s_res = 0u;
  __syncthreads();

  for (int b = 30; b >= 0; b -= 2) {
    const unsigned res = s_res;
    const unsigned t1 = res | (1u << b);
    const unsigned t2 = res | (2u << b);
    const unsigned t3 = res | (3u << b);
    unsigned c1 = 0, c2 = 0, c3 = 0;
#pragma unroll
    for (int j = 0; j < 16; ++j) {
      unsigned k = kloc[j];
      c1 += (k < t1); c2 += (k < t2); c3 += (k < t3);
    }
#pragma unroll
    for (int off = 32; off; off >>= 1) {
      c1 += __shfl_xor(c1, off);
      c2 += __shfl_xor(c2, off);
      c3 += __shfl_xor(c3, off);
    }
    if (lane == 0) { wred1[wave] = c1; wred2[wave] = c2; wred3[wave] = c3; }
    __syncthreads();
    if (tid == 0) {
      unsigned C1 = 0, C2 = 0, C3 = 0;
      for (int w = 0; w < 16; ++w) { C1 += wred1[w]; C2 += wred2[w]; C3 += wred3[w]; }
      unsigned nr = res;
      if (C3 <= RANK_TARGET)      nr = t3;
      else if (C2 <= RANK_TARGET) nr = t2;
      else if (C1 <= RANK_TARGET) nr = t1;
      s_res = nr;
    }
    __syncthreads();
  }

  // thre + S (register-resident A1 values; sum order fixed)
  const unsigned key = s_res;
  const unsigned bits = (key & 0x80000000u) ? (key ^ 0x80000000u) : ~key;
  const float thre = __uint_as_float(bits);
  float es = 0.f;
#pragma unroll
  for (int j = 0; j < 16; ++j) {
    float x = a1l[j]; x = (x > thre) ? x : 0.f;
    es += expf(x - thre);
  }
#pragma unroll
  for (int off = 32; off; off >>= 1) es += __shfl_xor(es, off);
  if (lane == 0) fred[wave] = es;
  __syncthreads();
  if (tid == 0) {
    float S = 0.f;
    for (int w = 0; w < 16; ++w) S += fred[w];
    scf[0] = thre;
    scf[2] = S;
  }
}

// ---------------------------------------------------------------------------
// Kernel 4: attn[r] = exp(thr(A1[r])-thre)/S directly (invZ known upfront);
// z[c] += attn[r]*qt[r,c] (normalized). LAST block computes y = z.cls_w + b.
// 256 blocks x 256 threads.
// ---------------------------------------------------------------------------
__global__ __launch_bounds__(256)
void expz_fin(const float* __restrict__ A1, const float* __restrict__ qt,
              const float* __restrict__ scf, float* __restrict__ e_out,
              float* __restrict__ z, const float* __restrict__ cls_w,
              const float* __restrict__ cls_b, float* __restrict__ y,
              unsigned* __restrict__ cnt) {
  __shared__ float vpart[4][512];
  __shared__ unsigned s_t;
  const int tid = threadIdx.x, lane = tid & 63, wave = tid >> 6;
  const float thre = scf[0];
  const float invZ = 1.f / scf[2];
  const int gw = blockIdx.x * 4 + wave;
  const int tw = 256 * 4;
  float acc[8] = {0, 0, 0, 0, 0, 0, 0, 0};
  for (int r = gw; r < NQ; r += tw) {
    float x = A1[r]; x = (x > thre) ? x : 0.f;
    float e = expf(x - thre) * invZ;              // == old finalize arithmetic
    if (lane == 0) e_out[r] = e;
    const float4* p = (const float4*)(qt + (size_t)r * HD + lane * 8);
    float4 u = p[0], w = p[1];
    acc[0] += e * u.x; acc[1] += e * u.y; acc[2] += e * u.z; acc[3] += e * u.w;
    acc[4] += e * w.x; acc[5] += e * w.y; acc[6] += e * w.z; acc[7] += e * w.w;
  }
#pragma unroll
  for (int j = 0; j < 8; ++j) vpart[wave][lane * 8 + j] = acc[j];
  __syncthreads();
  for (int c = tid; c < 512; c += 256)
    atomicAdd(&z[c], vpart[0][c] + vpart[1][c] + vpart[2][c] + vpart[3][c]);

  // last-block ticket: only y remains (512 floats)
  __threadfence();
  __syncthreads();
  if (tid == 0) s_t = atomicAdd(cnt, 1u);
  __syncthreads();
  if (s_t != 255) return;
  __threadfence();                               // acquire side

  if (tid < 64) {
    volatile const float* zv = z;
    float dot = 0.f;
#pragma unroll
    for (int j = 0; j < 8; ++j)
      dot += zv[tid * 8 + j] * cls_w[tid * 8 + j];
#pragma unroll
    for (int off = 32; off; off >>= 1) dot += __shfl_xor(dot, off);
    if (tid == 0) y[0] = dot + cls_b[0];
  }
}

// ---------------------------------------------------------------------------
// Workspace layout (bytes). Max end = 52,498,688.
// v/z/scf contiguous (zeroed as 1088 uints by conv_wk block 0); tickets live
// at scf[8] and scf[9] (inside the zeroed region -> replay-safe).
// ---------------------------------------------------------------------------
#define OFF_WQBF 0u
#define OFF_WKBF 1048576u
#define OFF_KBF  2097152u      // 16.25 MB, ends 18,343,936
#define OFF_QT   18874368u     // 33.55 MB, ends 52,428,800
#define OFF_A1   52428800u     // 64 KB
#define OFF_V    52494336u     // 2 KB
#define OFF_Z    52496384u     // 2 KB
#define OFF_SC   52498432u     // 256 B, ends 52,498,688

extern "C" void kernel_launch(void* const* d_in, const int* in_sizes, int n_in,
                              void* d_out, int out_size, void* d_ws, size_t ws_size,
                              hipStream_t stream) {
  const float* query = (const float*)d_in[0];
  const float* key_x = (const float*)d_in[1];
  const float* wq_w  = (const float*)d_in[2];
  const float* wq_b  = (const float*)d_in[3];
  const float* wk_w  = (const float*)d_in[4];
  const float* wk_b  = (const float*)d_in[5];
  const float* wa_w  = (const float*)d_in[6];
  const float* wa_b  = (const float*)d_in[7];
  const float* cls_w = (const float*)d_in[8];
  const float* cls_b = (const float*)d_in[9];
  float* out = (float*)d_out;

  char* ws = (char*)d_ws;
  __bf16* wqbf  = (__bf16*)(ws + OFF_WQBF);
  __bf16* wkbf  = (__bf16*)(ws + OFF_WKBF);
  __bf16* kbf   = (__bf16*)(ws + OFF_KBF);
  float*  qtanh = (float*)(ws + OFF_QT);
  float*  A1    = (float*)(ws + OFF_A1);
  float*  v     = (float*)(ws + OFF_V);
  float*  z     = (float*)(ws + OFF_Z);
  float*  scf   = (float*)(ws + OFF_SC);
  unsigned* cnt1 = (unsigned*)(scf + 8);
  unsigned* cnt2 = (unsigned*)(scf + 9);
  float*  out_attn = out + 1;

  // 1: convert key + weights to bf16; zero v/z/scf (incl. tickets)
  conv_wk<<<2048, 256, 0, stream>>>(wq_w, wk_w, key_x, wqbf, wkbf, kbf,
                                    (unsigned*)v);

  // 2: mega launch — k-GEMM (fused v) co-scheduled with q-GEMM (r9 version)
  mega_gemms<<<636, 512, 0, stream>>>(kbf, wkbf, wk_b, wa_w, v,
                                      query, wqbf, wq_b, qtanh);

  // 3: A1 pass (16-lane-group rows) + last-block select + S
  a1_select<<<256, 1024, 0, stream>>>(qtanh, v, wa_b, A1, scf, cnt1);

  // 4: normalized expz + last-block y
  expz_fin<<<256, 256, 0, stream>>>(A1, qtanh, scf, out_attn, z,
                                    cls_w, cls_b, out, cnt2);
}

// Round 12
// 245.961 us; speedup vs baseline: 1.3988x; 1.3988x over previous
//
#include <hip/hip_runtime.h>
#include <math.h>

// Problem constants (match reference)
#define NQ 16384
#define NK 7933
#define DI 1024
#define HD 512
#define RANK_TARGET 11469   // NQ - int(0.3*NQ): 0-based ascending rank of thre

typedef __bf16 bf16x8 __attribute__((ext_vector_type(8)));
typedef float  f32x4  __attribute__((ext_vector_type(4)));

#define GLOAD_LDS16(g, l)                                                     \
  __builtin_amdgcn_global_load_lds(                                           \
      (const __attribute__((address_space(1))) void*)(g),                     \
      (__attribute__((address_space(3))) void*)(l), 16, 0, 0)

__device__ __forceinline__ unsigned mapf(float f) {
  unsigned b = __float_as_uint(f);
  return (b & 0x80000000u) ? ~b : (b | 0x80000000u);
}

__device__ __forceinline__ bf16x8 cvt8(float4 a, float4 b) {
  bf16x8 o;
  o[0] = (__bf16)a.x; o[1] = (__bf16)a.y; o[2] = (__bf16)a.z; o[3] = (__bf16)a.w;
  o[4] = (__bf16)b.x; o[5] = (__bf16)b.y; o[6] = (__bf16)b.z; o[7] = (__bf16)b.w;
  return o;
}

// ---------------------------------------------------------------------------
// Kernel 1: fp32 -> bf16 for wq_w, wk_w, key_x. Block 0 zeroes v/z/scf
// (1088 uints: v[512], z[512], scf[64]).
// ---------------------------------------------------------------------------
__global__ void conv_wk(const float* __restrict__ wq, const float* __restrict__ wk,
                        const float* __restrict__ key,
                        __bf16* __restrict__ wqbf, __bf16* __restrict__ wkbf,
                        __bf16* __restrict__ kbf, unsigned* __restrict__ zero_region) {
  if (blockIdx.x == 0) {
    for (int j = threadIdx.x; j < 1088; j += 256) zero_region[j] = 0u;
  }
  const int NK8 = NK * DI / 8;   // 1,015,424
  const int W8  = HD * DI / 8;   // 65,536
  const int total = NK8 + 2 * W8;
  int i = blockIdx.x * blockDim.x + threadIdx.x;
  int stride = gridDim.x * blockDim.x;
  for (; i < total; i += stride) {
    const float* s; __bf16* d; int j;
    if (i < NK8)            { s = key; d = kbf;  j = i; }
    else if (i < NK8 + W8)  { s = wq;  d = wqbf; j = i - NK8; }
    else                    { s = wk;  d = wkbf; j = i - NK8 - W8; }
    float4 a = ((const float4*)s)[2 * j];
    float4 b = ((const float4*)s)[2 * j + 1];
    ((bf16x8*)d)[j] = cvt8(a, b);
  }
}

// ---------------------------------------------------------------------------
// Mega kernel (r9-identical, 76 µs measured), 636 blocks x 512 threads,
// 80 KB LDS -> 2 blocks/CU. Blocks 0..123: k-GEMM 64x512 (BK=64, sA dbuf +
// sB single-buffer, fused v epilogue; ssrow aliases dead sA).
// Blocks 124..635: q-GEMM 64x256 reading fp32 query directly.
// ---------------------------------------------------------------------------
__global__ __launch_bounds__(512, 4)
void mega_gemms(const __bf16* __restrict__ kbf, const __bf16* __restrict__ wkbf,
                const float* __restrict__ wk_b, const float* __restrict__ wa,
                float* __restrict__ v,
                const float* __restrict__ query, const __bf16* __restrict__ wqbf,
                const float* __restrict__ wq_b, float* __restrict__ qtanh) {
  __shared__ __align__(16) char smem[81920];
  const int bid = blockIdx.x;
  const int tid = threadIdx.x;
  const int lane = tid & 63;
  const int wave = tid >> 6;                    // 0..7
  const int srow = lane >> 3;                   // 0..7 row within segment
  const int scol = ((lane & 7) ^ srow) << 3;    // swizzled col (bf16 units)
  const int lrow = lane & 15;
  const int chi  = lane >> 4;                   // 0..3
  constexpr int K = DI;

  if (bid < 124) {
    // ---------------- k path: 64x512 tile, fused v epilogue ----------------
    __bf16* sA = (__bf16*)smem;                 // 2 x 4096 elems (16 KB dbuf)
    __bf16* sB = (__bf16*)(smem + 16384);       // 32768 elems (64 KB single)
    float* ssrow = (float*)smem;                // aliases sA (dead after K-loop)
    const int m0 = bid * 64;

    int gaA = m0 + wave * 8 + srow; if (gaA > NK - 1) gaA = NK - 1;
    const __bf16* Ap = kbf + (size_t)gaA * K + scol;
    const __bf16* Bp[8];
#pragma unroll
    for (int c = 0; c < 8; ++c)
      Bp[c] = wkbf + (size_t)(wave * 64 + c * 8 + srow) * K + scol;

    f32x4 acc[4][4] = {};

    GLOAD_LDS16(Ap, &sA[wave * 512]);
#pragma unroll
    for (int c = 0; c < 8; ++c)
      GLOAD_LDS16(Bp[c], &sB[(wave * 8 + c) * 512]);
    __syncthreads();

    int buf = 0;
    for (int t = 0; t < 16; ++t) {
      const int kk = t * 64;
      if (t < 15)
        GLOAD_LDS16(Ap + kk + 64, &sA[(buf ^ 1) * 4096 + wave * 512]);
      const __bf16* sAc = sA + buf * 4096;
#pragma unroll
      for (int ks = 0; ks < 64; ks += 32) {
        const int cc = (ks >> 3) + chi;
        const int sw = ((cc ^ (lrow & 7)) << 3);
        bf16x8 af[4], bfr[4];
#pragma unroll
        for (int mi = 0; mi < 4; ++mi)
          af[mi] = *(const bf16x8*)(&sAc[(mi * 16 + lrow) * 64 + sw]);
#pragma unroll
        for (int ni = 0; ni < 4; ++ni)
          bfr[ni] = *(const bf16x8*)(&sB[(wave * 64 + ni * 16 + lrow) * 64 + sw]);
#pragma unroll
        for (int mi = 0; mi < 4; ++mi)
#pragma unroll
          for (int ni = 0; ni < 4; ++ni)
            acc[mi][ni] = __builtin_amdgcn_mfma_f32_16x16x32_bf16(af[mi], bfr[ni], acc[mi][ni], 0, 0, 0);
      }
      if (t < 15) {
        __syncthreads();                 // sB readers done; A(t+1) landed
#pragma unroll
        for (int c = 0; c < 8; ++c)      // overwrite sB with B(t+1)
          GLOAD_LDS16(Bp[c] + kk + 64, &sB[(wave * 8 + c) * 512]);
        __syncthreads();                 // B(t+1) resident
        buf ^= 1;
      }
    }

    // fused epilogue: tanh, row-norm, v accumulation (no ktanh store)
    __syncthreads();                     // all sA reads retired before aliasing
    if (tid < 64) ssrow[tid] = 0.f;
    __syncthreads();

    float b4[4];
#pragma unroll
    for (int ni = 0; ni < 4; ++ni) b4[ni] = wk_b[wave * 64 + ni * 16 + lrow];

#pragma unroll
    for (int mi = 0; mi < 4; ++mi)
#pragma unroll
      for (int ni = 0; ni < 4; ++ni)
#pragma unroll
        for (int r = 0; r < 4; ++r)
          acc[mi][ni][r] = tanhf(acc[mi][ni][r] + b4[ni]);

#pragma unroll
    for (int mi = 0; mi < 4; ++mi)
#pragma unroll
      for (int r = 0; r < 4; ++r) {
        float ps = 0.f;
#pragma unroll
        for (int ni = 0; ni < 4; ++ni) ps += acc[mi][ni][r] * acc[mi][ni][r];
#pragma unroll
        for (int off = 1; off < 16; off <<= 1) ps += __shfl_xor(ps, off);
        if ((lane & 15) == 0)
          atomicAdd(&ssrow[mi * 16 + (lane >> 4) * 4 + r], ps);
      }
    __syncthreads();

    if (tid < 64) {
      int grow = m0 + tid;
      float s = 0.f;
      if (grow < NK) s = wa[grow] / fmaxf(sqrtf(ssrow[tid]), 1e-12f);
      ssrow[tid] = s;                    // replace ss with scale (0 for tail)
    }
    __syncthreads();

    float sc[4][4];
#pragma unroll
    for (int mi = 0; mi < 4; ++mi)
#pragma unroll
      for (int r = 0; r < 4; ++r)
        sc[mi][r] = ssrow[mi * 16 + (lane >> 4) * 4 + r];

#pragma unroll
    for (int ni = 0; ni < 4; ++ni) {
      float cs = 0.f;
#pragma unroll
      for (int mi = 0; mi < 4; ++mi)
#pragma unroll
        for (int r = 0; r < 4; ++r)
          cs += acc[mi][ni][r] * sc[mi][r];
      cs += __shfl_xor(cs, 16);
      cs += __shfl_xor(cs, 32);
      if (lane < 16) atomicAdd(&v[wave * 64 + ni * 16 + lane], cs);
    }
  } else {
    // ---------------- q path: 64x256 tile, fp32 A from global --------------
    __bf16* sA = (__bf16*)smem;                 // 2 x 4096 elems (16 KB dbuf)
    __bf16* sB = (__bf16*)(smem + 16384);       // 2 x 16384 elems (64 KB dbuf)
    const int qi = bid - 124;                   // 0..511
    const int m0 = (qi >> 1) * 64;
    const int n0 = (qi & 1) * 256;
    const int wr = wave >> 2;                   // 0..1
    const int wc = wave & 3;                    // 0..3

    const int arow = tid >> 3;                  // 0..63
    const int acb  = tid & 7;                   // 0..7
    const int aoff = arow * 64 + ((acb ^ (arow & 7)) << 3);
    const float* ap = query + (size_t)(m0 + arow) * K + acb * 8;

    const __bf16* Bp0 = wqbf + (size_t)(n0 + (wave * 4 + 0) * 8 + srow) * K + scol;
    const __bf16* Bp1 = wqbf + (size_t)(n0 + (wave * 4 + 1) * 8 + srow) * K + scol;
    const __bf16* Bp2 = wqbf + (size_t)(n0 + (wave * 4 + 2) * 8 + srow) * K + scol;
    const __bf16* Bp3 = wqbf + (size_t)(n0 + (wave * 4 + 3) * 8 + srow) * K + scol;

    f32x4 acc[2][4] = {};

    {  // prologue: stage tile 0
      float4 x0 = *(const float4*)(ap);
      float4 x1 = *(const float4*)(ap + 4);
      GLOAD_LDS16(Bp0, &sB[(wave * 4 + 0) * 512]);
      GLOAD_LDS16(Bp1, &sB[(wave * 4 + 1) * 512]);
      GLOAD_LDS16(Bp2, &sB[(wave * 4 + 2) * 512]);
      GLOAD_LDS16(Bp3, &sB[(wave * 4 + 3) * 512]);
      *(bf16x8*)&sA[aoff] = cvt8(x0, x1);
      __syncthreads();
    }

    int buf = 0;
    for (int t = 0; t < 16; ++t) {
      const int kk = t * 64;
      float4 x0, x1;
      if (t < 15) {
        x0 = *(const float4*)(ap + kk + 64);     // A loads first (oldest VMEM)
        x1 = *(const float4*)(ap + kk + 68);
        const int ob = buf ^ 1;
        GLOAD_LDS16(Bp0 + kk + 64, &sB[ob * 16384 + (wave * 4 + 0) * 512]);
        GLOAD_LDS16(Bp1 + kk + 64, &sB[ob * 16384 + (wave * 4 + 1) * 512]);
        GLOAD_LDS16(Bp2 + kk + 64, &sB[ob * 16384 + (wave * 4 + 2) * 512]);
        GLOAD_LDS16(Bp3 + kk + 64, &sB[ob * 16384 + (wave * 4 + 3) * 512]);
      }
      const __bf16* sAc = sA + buf * 4096;
      const __bf16* sBc = sB + buf * 16384;
#pragma unroll
      for (int ks = 0; ks < 64; ks += 32) {
        const int cc = (ks >> 3) + chi;
        const int sw = ((cc ^ (lrow & 7)) << 3);
        bf16x8 af[2], bfr[4];
        af[0] = *(const bf16x8*)(&sAc[(wr * 32 + lrow) * 64 + sw]);
        af[1] = *(const bf16x8*)(&sAc[(wr * 32 + 16 + lrow) * 64 + sw]);
#pragma unroll
        for (int ni = 0; ni < 4; ++ni)
          bfr[ni] = *(const bf16x8*)(&sBc[(wc * 64 + ni * 16 + lrow) * 64 + sw]);
#pragma unroll
        for (int ni = 0; ni < 4; ++ni) {
          acc[0][ni] = __builtin_amdgcn_mfma_f32_16x16x32_bf16(af[0], bfr[ni], acc[0][ni], 0, 0, 0);
          acc[1][ni] = __builtin_amdgcn_mfma_f32_16x16x32_bf16(af[1], bfr[ni], acc[1][ni], 0, 0, 0);
        }
      }
      if (t < 15) {
        *(bf16x8*)&sA[(buf ^ 1) * 4096 + aoff] = cvt8(x0, x1);  // waits A regs
        __syncthreads();                  // retires B prefetch + sA write
        buf ^= 1;
      }
    }

    // epilogue: qtanh only (A1 handled by a1_pass)
    const int rbase = m0 + wr * 32 + ((lane >> 4) << 2);
    const int cbase = n0 + wc * 64 + (lane & 15);
    float b4[4];
#pragma unroll
    for (int ni = 0; ni < 4; ++ni) b4[ni] = wq_b[cbase + ni * 16];
#pragma unroll
    for (int mi = 0; mi < 2; ++mi)
#pragma unroll
      for (int r = 0; r < 4; ++r) {
        int grow = rbase + mi * 16 + r;
#pragma unroll
        for (int ni = 0; ni < 4; ++ni)
          qtanh[(size_t)grow * HD + cbase + ni * 16] =
              tanhf(acc[mi][ni][r] + b4[ni]);
      }
  }
}

// ---------------------------------------------------------------------------
// Kernel 3: A1[r] = (qtanh[r].v)/max(||qtanh[r]||,1e-12) + wa_b.
// 256 blocks x 1024 threads; each 16-lane group owns ONE row; row read as
// 8 fully-coalesced float4 chunks (chunk j: lane gl reads row4[j*16+gl]).
// Single sweep: 256 x 16 waves x 4 groups = 16384 rows. NO fences/tickets.
// ---------------------------------------------------------------------------
__global__ __launch_bounds__(1024)
void a1_pass(const float* __restrict__ qt, const float* __restrict__ v,
             const float* __restrict__ wa_b, float* __restrict__ A1) {
  const int tid = threadIdx.x, lane = tid & 63, wave = tid >> 6;  // wave 0..15
  const int grp = lane >> 4;                   // 0..3: row group within wave
  const int gl  = lane & 15;                   // lane within group
  const float wab = wa_b[0];

  // preload v: chunk j covers floats j*64 + gl*4 .. +3 (coalesced)
  const float4* v4 = (const float4*)v;
  float4 vj[8];
#pragma unroll
  for (int j = 0; j < 8; ++j) vj[j] = v4[j * 16 + gl];

  const int r = blockIdx.x * 64 + wave * 4 + grp;        // 0..16383, unique
  const float4* row4 = (const float4*)(qt + (size_t)r * HD);
  float dot = 0.f, ss = 0.f;
#pragma unroll
  for (int j = 0; j < 8; ++j) {
    float4 u = row4[j * 16 + gl];
    dot += u.x * vj[j].x + u.y * vj[j].y + u.z * vj[j].z + u.w * vj[j].w;
    ss  += u.x * u.x + u.y * u.y + u.z * u.z + u.w * u.w;
  }
#pragma unroll
  for (int off = 1; off < 16; off <<= 1) {
    dot += __shfl_xor(dot, off);
    ss  += __shfl_xor(ss, off);
  }
  if (gl == 0) A1[r] = dot / fmaxf(sqrtf(ss), 1e-12f) + wab;
}

// ---------------------------------------------------------------------------
// Kernel 4: single block, 1024 threads. Exact rank-11469 select over A1,
// then thre AND S = sum(exp(thr(A1)-thre)) -> scf[0], scf[2].
// (r11-verified arithmetic, now its own launch — no fences.)
// ---------------------------------------------------------------------------
__global__ __launch_bounds__(1024)
void select_s(const float* __restrict__ A1, float* __restrict__ scf) {
  __shared__ unsigned wred1[16], wred2[16], wred3[16];
  __shared__ float fred[16];
  __shared__ unsigned s_res;
  const int tid = threadIdx.x, lane = tid & 63, wave = tid >> 6;
  float a1l[16];
  unsigned kloc[16];
#pragma unroll 4
  for (int j = 0; j < 16; ++j) {
    float x = A1[j * 1024 + tid];
    a1l[j] = x;
    kloc[j] = mapf(x);
  }
  if (tid == 0) s_res = 0u;
  __syncthreads();

  for (int b = 30; b >= 0; b -= 2) {
    const unsigned res = s_res;
    const unsigned t1 = res | (1u << b);
    const unsigned t2 = res | (2u << b);
    const unsigned t3 = res | (3u << b);
    unsigned c1 = 0, c2 = 0, c3 = 0;
#pragma unroll
    for (int j = 0; j < 16; ++j) {
      unsigned k = kloc[j];
      c1 += (k < t1); c2 += (k < t2); c3 += (k < t3);
    }
#pragma unroll
    for (int off = 32; off; off >>= 1) {
      c1 += __shfl_xor(c1, off);
      c2 += __shfl_xor(c2, off);
      c3 += __shfl_xor(c3, off);
    }
    if (lane == 0) { wred1[wave] = c1; wred2[wave] = c2; wred3[wave] = c3; }
    __syncthreads();
    if (tid == 0) {
      unsigned C1 = 0, C2 = 0, C3 = 0;
      for (int w = 0; w < 16; ++w) { C1 += wred1[w]; C2 += wred2[w]; C3 += wred3[w]; }
      unsigned nr = res;
      if (C3 <= RANK_TARGET)      nr = t3;
      else if (C2 <= RANK_TARGET) nr = t2;
      else if (C1 <= RANK_TARGET) nr = t1;
      s_res = nr;
    }
    __syncthreads();
  }

  // thre + S (register-resident A1 values)
  const unsigned key = s_res;
  const unsigned bits = (key & 0x80000000u) ? (key ^ 0x80000000u) : ~key;
  const float thre = __uint_as_float(bits);
  float es = 0.f;
#pragma unroll
  for (int j = 0; j < 16; ++j) {
    float x = a1l[j]; x = (x > thre) ? x : 0.f;
    es += expf(x - thre);
  }
#pragma unroll
  for (int off = 32; off; off >>= 1) es += __shfl_xor(es, off);
  if (lane == 0) fred[wave] = es;
  __syncthreads();
  if (tid == 0) {
    float S = 0.f;
    for (int w = 0; w < 16; ++w) S += fred[w];
    scf[0] = thre;
    scf[2] = S;
  }
}

// ---------------------------------------------------------------------------
// Kernel 5: attn[r] = exp(thr(A1[r])-thre)/S directly (invZ known upfront);
// z[c] += attn[r]*qt[r,c] (normalized). 256 blocks x 256 threads.
// ---------------------------------------------------------------------------
__global__ __launch_bounds__(256)
void expz_n(const float* __restrict__ A1, const float* __restrict__ qt,
            const float* __restrict__ scf, float* __restrict__ e_out,
            float* __restrict__ z) {
  __shared__ float vpart[4][512];
  const int tid = threadIdx.x, lane = tid & 63, wave = tid >> 6;
  const float thre = scf[0];
  const float invZ = 1.f / scf[2];
  const int gw = blockIdx.x * 4 + wave;
  const int tw = 256 * 4;
  float acc[8] = {0, 0, 0, 0, 0, 0, 0, 0};
  for (int r = gw; r < NQ; r += tw) {
    float x = A1[r]; x = (x > thre) ? x : 0.f;
    float e = expf(x - thre) * invZ;              // == r7 finalize arithmetic
    if (lane == 0) e_out[r] = e;
    const float4* p = (const float4*)(qt + (size_t)r * HD + lane * 8);
    float4 u = p[0], w = p[1];
    acc[0] += e * u.x; acc[1] += e * u.y; acc[2] += e * u.z; acc[3] += e * u.w;
    acc[4] += e * w.x; acc[5] += e * w.y; acc[6] += e * w.z; acc[7] += e * w.w;
  }
#pragma unroll
  for (int j = 0; j < 8; ++j) vpart[wave][lane * 8 + j] = acc[j];
  __syncthreads();
  for (int c = tid; c < 512; c += 256)
    atomicAdd(&z[c], vpart[0][c] + vpart[1][c] + vpart[2][c] + vpart[3][c]);
}

// ---------------------------------------------------------------------------
// Kernel 6: y = z.cls_w + cls_b (z already invZ-normalized). 1 block, 64 thr.
// ---------------------------------------------------------------------------
__global__ __launch_bounds__(64)
void y_fin(const float* __restrict__ z, const float* __restrict__ cls_w,
           const float* __restrict__ cls_b, float* __restrict__ y) {
  const int lane = threadIdx.x;
  const float4* zp = (const float4*)(z + lane * 8);
  const float4* wp = (const float4*)(cls_w + lane * 8);
  float4 a = zp[0], b = zp[1], c = wp[0], d = wp[1];
  float dot = a.x * c.x + a.y * c.y + a.z * c.z + a.w * c.w
            + b.x * d.x + b.y * d.y + b.z * d.z + b.w * d.w;
#pragma unroll
  for (int off = 32; off; off >>= 1) dot += __shfl_xor(dot, off);
  if (lane == 0) y[0] = dot + cls_b[0];
}

// ---------------------------------------------------------------------------
// Workspace layout (bytes). Max end = 52,498,688.
// v/z/scf contiguous (zeroed as 1088 uints by conv_wk block 0).
// ---------------------------------------------------------------------------
#define OFF_WQBF 0u
#define OFF_WKBF 1048576u
#define OFF_KBF  2097152u      // 16.25 MB, ends 18,343,936
#define OFF_QT   18874368u     // 33.55 MB, ends 52,428,800
#define OFF_A1   52428800u     // 64 KB
#define OFF_V    52494336u     // 2 KB
#define OFF_Z    52496384u     // 2 KB
#define OFF_SC   52498432u     // 256 B, ends 52,498,688

extern "C" void kernel_launch(void* const* d_in, const int* in_sizes, int n_in,
                              void* d_out, int out_size, void* d_ws, size_t ws_size,
                              hipStream_t stream) {
  const float* query = (const float*)d_in[0];
  const float* key_x = (const float*)d_in[1];
  const float* wq_w  = (const float*)d_in[2];
  const float* wq_b  = (const float*)d_in[3];
  const float* wk_w  = (const float*)d_in[4];
  const float* wk_b  = (const float*)d_in[5];
  const float* wa_w  = (const float*)d_in[6];
  const float* wa_b  = (const float*)d_in[7];
  const float* cls_w = (const float*)d_in[8];
  const float* cls_b = (const float*)d_in[9];
  float* out = (float*)d_out;

  char* ws = (char*)d_ws;
  __bf16* wqbf  = (__bf16*)(ws + OFF_WQBF);
  __bf16* wkbf  = (__bf16*)(ws + OFF_WKBF);
  __bf16* kbf   = (__bf16*)(ws + OFF_KBF);
  float*  qtanh = (float*)(ws + OFF_QT);
  float*  A1    = (float*)(ws + OFF_A1);
  float*  v     = (float*)(ws + OFF_V);
  float*  z     = (float*)(ws + OFF_Z);
  float*  scf   = (float*)(ws + OFF_SC);
  float*  out_attn = out + 1;

  // 1: convert key + weights to bf16; zero v/z/scf
  conv_wk<<<2048, 256, 0, stream>>>(wq_w, wk_w, key_x, wqbf, wkbf, kbf,
                                    (unsigned*)v);

  // 2: mega launch — k-GEMM (fused v) co-scheduled with q-GEMM (r9 version)
  mega_gemms<<<636, 512, 0, stream>>>(kbf, wkbf, wk_b, wa_w, v,
                                      query, wqbf, wq_b, qtanh);

  // 3: A1 pass (coalesced 16-lane-group rows, single sweep)
  a1_pass<<<256, 1024, 0, stream>>>(qtanh, v, wa_b, A1);

  // 4: rank-11469 select + thre + S (single block)
  select_s<<<1, 1024, 0, stream>>>(A1, scf);

  // 5: normalized expz (attn written final; z accumulated normalized)
  expz_n<<<256, 256, 0, stream>>>(A1, qtanh, scf, out_attn, z);

  // 6: y from z
  y_fin<<<1, 64, 0, stream>>>(z, cls_w, cls_b, out);
}